// Round 4
// baseline (129.206 us; speedup 1.0000x reference)
//
#include <hip/hip_runtime.h>

#define NEWL 150
#define EMBD 64
#define NCOL 256
#define CIMU 48
#define CEMG 16

#define KIMU (NEWL * CIMU)  // 7200
#define KEMG (NEWL * CEMG)  // 2400
#define KSTI (KIMU / 32)    // 225 k-steps imu
#define KSTE (KEMG / 32)    // 75  k-steps emg
#define KSC 25              // k-steps per split-K chunk (K=800)
#define NCI (KSTI / KSC)    // 9 imu chunks
#define NCE (KSTE / KSC)    // 3 emg chunks

typedef __bf16 bf16x8_t __attribute__((ext_vector_type(8)));
typedef __bf16 bf16x4_t __attribute__((ext_vector_type(4)));
typedef float f32x4_t __attribute__((ext_vector_type(4)));

__device__ __forceinline__ f32x4_t mfma16(bf16x8_t a, bf16x8_t b, f32x4_t c) {
  return __builtin_amdgcn_mfma_f32_16x16x32_bf16(a, b, c, 0, 0, 0);
}

// ---------- K0: combined weights packed in MFMA B-fragment order + bias partials.
// W_pack[cb][ks][lane=h*16+(col&15)][u]  where k = ks*32 + h*8 + u
template <int C, int KST>
__device__ void wcomb_body(const float* __restrict__ wemb,
                           const float* __restrict__ wreg_src,
                           __bf16* __restrict__ wpk, int s, int j) {
  float wreg[EMBD];
#pragma unroll
  for (int e = 0; e < EMBD; ++e) wreg[e] = wreg_src[(size_t)e * NCOL];
  const int cb = j >> 4, lr = j & 15;
#pragma unroll
  for (int q = 0; q < C / 8; ++q) {
    const int kq = (s * C) / 8 + q;  // k/8
    const int ks = kq >> 2, h = kq & 3;
    bf16x8_t tv;
#pragma unroll
    for (int u = 0; u < 8; ++u) {
      const float* we = wemb + (q * 8 + u) * EMBD;
      float acc = 0.f;
#pragma unroll
      for (int e = 0; e < EMBD; ++e) acc = fmaf(we[e], wreg[e], acc);
      tv[u] = (__bf16)acc;
    }
    *(bf16x8_t*)(wpk + (((size_t)cb * KST + ks) * 64 + h * 16 + lr) * 8) = tv;
  }
}

__global__ __launch_bounds__(256) void wcomb_kernel(
    const float* __restrict__ w_emb_imu, const float* __restrict__ w_emb_emg,
    const float* __restrict__ b_emb_imu, const float* __restrict__ b_emb_emg,
    const float* __restrict__ w_proj,
    __bf16* __restrict__ wpk_imu, __bf16* __restrict__ wpk_emg,
    float* __restrict__ bpart) {
  const int s = blockIdx.x;   // 0..149
  const int m = blockIdx.y;   // 0 = imu, 1 = emg
  const int j = threadIdx.x;  // output column 0..255
  const float* wp_base = w_proj + (size_t)s * EMBD * NCOL + j;
  const float* be = (m == 0) ? b_emb_imu : b_emb_emg;
  float bacc = 0.f;
#pragma unroll
  for (int e = 0; e < EMBD; ++e) bacc = fmaf(be[e], wp_base[(size_t)e * NCOL], bacc);
  bpart[((size_t)m * NEWL + s) * NCOL + j] = bacc;
  if (m == 0)
    wcomb_body<CIMU, KSTI>(w_emb_imu, wp_base, wpk_imu, s, j);
  else
    wcomb_body<CEMG, KSTE>(w_emb_emg, wp_base, wpk_emg, s, j);
}

__global__ __launch_bounds__(256) void bias_reduce_kernel(
    const float* __restrict__ b_proj, const float* __restrict__ bpart,
    float* __restrict__ bias) {
  const int m = blockIdx.x, j = threadIdx.x;
  float acc = b_proj[j];
  for (int s = 0; s < NEWL; ++s) acc += bpart[((size_t)m * NEWL + s) * NCOL + j];
  bias[m * NCOL + j] = acc;
}

// ---------- K2: ragged interp, float4 gather, output written in MFMA
// A-fragment packed order: A_pk[mb][ks][lane=h*16+(b&15)][u], k = ks*32+h*8+u
__global__ __launch_bounds__(256) void interp_kernel(
    const float* __restrict__ x_imu, const float* __restrict__ x_emg,
    const int* __restrict__ lens,
    __bf16* __restrict__ xa_imu, __bf16* __restrict__ xa_emg, int B, int T) {
  const int tid = threadIdx.x;
  const int g32 = blockIdx.x * 8 + (tid >> 5);  // one 32-lane group per (b,s)
  const int lane = tid & 63;
  const int g = tid & 31;
  const int b = g32 / NEWL;
  const int s = g32 - b * NEWL;
  if (b >= B) return;
  const int len = lens[b];
  const float scale = (float)len / 150.0f;
  float src = ((float)s + 0.5f) * scale - 0.5f;
  src = fmaxf(src, 0.0f);
  int i0 = (int)floorf(src);
  i0 = min(i0, len - 1);
  const int i1 = min(i0 + 1, len - 1);
  const float w = src - (float)i0;

  float4 v;
  if (g < 24) {  // imu: g<12 -> row i0 chunk g ; 12..23 -> row i1 chunk g-12
    const int ci = (g < 12) ? g : g - 12;
    const int ir = (g < 12) ? i0 : i1;
    v = *(const float4*)(x_imu + ((size_t)b * T + ir) * CIMU + ci * 4);
  } else {       // emg: 24..27 -> i0 chunk g-24 ; 28..31 -> i1 chunk g-28
    const int ci = g & 3;
    const int ir = (g < 28) ? i0 : i1;
    v = *(const float4*)(x_emg + ((size_t)b * T + ir) * CEMG + ci * 4);
  }
  const int base = lane & 32;
  const int src_lane = (g < 24) ? (base + g + 12) : (base + g + 4);
  float4 pv;
  pv.x = __shfl(v.x, src_lane);
  pv.y = __shfl(v.y, src_lane);
  pv.z = __shfl(v.z, src_lane);
  pv.w = __shfl(v.w, src_lane);

  bf16x4_t o;
  o[0] = (__bf16)(v.x * (1.0f - w) + pv.x * w);
  o[1] = (__bf16)(v.y * (1.0f - w) + pv.y * w);
  o[2] = (__bf16)(v.z * (1.0f - w) + pv.z * w);
  o[3] = (__bf16)(v.w * (1.0f - w) + pv.w * w);

  const int mb = b >> 4, r = b & 15;
  if (g < 12) {
    const int k0 = s * CIMU + g * 4;  // 48s ≡ 0 (mod 16) -> u ∈ {0,4}
    const int ks = k0 >> 5, h = (k0 >> 3) & 3, u = k0 & 7;
    *(bf16x4_t*)(xa_imu + (((size_t)mb * KSTI + ks) * 64 + h * 16 + r) * 8 + u) = o;
  } else if (g >= 24 && g < 28) {
    const int k0 = s * CEMG + (g - 24) * 4;  // 16s ≡ 0 (mod 16)
    const int ks = k0 >> 5, h = (k0 >> 3) & 3, u = k0 & 7;
    *(bf16x4_t*)(xa_emg + (((size_t)mb * KSTE + ks) * 64 + h * 16 + r) * 8 + u) = o;
  }
}

// ---------- K3: pure streaming MFMA GEMM — both operands fragment-packed,
// no LDS, no barriers. Wave tile 32x64 (2 row-planes x 4 col-planes).
__global__ __launch_bounds__(256) void mfma_gemm_kernel(
    const __bf16* __restrict__ xa_imu, const __bf16* __restrict__ xa_emg,
    const __bf16* __restrict__ wpk_imu, const __bf16* __restrict__ wpk_emg,
    float* __restrict__ p_imu, float* __restrict__ p_emg, int B) {
  const int upc = (B >> 5) * 4;  // 256 wave-units per k-chunk
  const int u = blockIdx.x * 4 + (threadIdx.x >> 6);
  const int c = u / upc;
  const int t = u - c * upc;
  const int mw = t >> 2, nb4 = t & 3;

  const __bf16* A;
  const __bf16* Wp;
  float* P;
  int KST, kc;
  if (c < NCI) {
    kc = c; A = xa_imu; Wp = wpk_imu; KST = KSTI;
    P = p_imu + (size_t)kc * B * NCOL;
  } else {
    kc = c - NCI; A = xa_emg; Wp = wpk_emg; KST = KSTE;
    P = p_emg + (size_t)kc * B * NCOL;
  }
  const int ks0 = kc * KSC;
  const int l = threadIdx.x & 63;

  const size_t plane = (size_t)KST * 64 * 8;  // bf16 per fragment plane
  const __bf16* ap0 = A + (size_t)(mw * 2) * plane + ((size_t)ks0 * 64 + l) * 8;
  const __bf16* ap1 = ap0 + plane;
  const __bf16* bg = Wp + (size_t)(nb4 * 4) * plane + ((size_t)ks0 * 64 + l) * 8;

  f32x4_t z = {0.f, 0.f, 0.f, 0.f};
  f32x4_t acc[2][4];
#pragma unroll
  for (int i = 0; i < 2; ++i)
#pragma unroll
    for (int jj = 0; jj < 4; ++jj) acc[i][jj] = z;

#pragma unroll 5
  for (int ks = 0; ks < KSC; ++ks) {
    const size_t o = (size_t)ks * 512;
    const bf16x8_t av0 = *(const bf16x8_t*)(ap0 + o);
    const bf16x8_t av1 = *(const bf16x8_t*)(ap1 + o);
    const bf16x8_t bv0 = *(const bf16x8_t*)(bg + o);
    const bf16x8_t bv1 = *(const bf16x8_t*)(bg + plane + o);
    const bf16x8_t bv2 = *(const bf16x8_t*)(bg + 2 * plane + o);
    const bf16x8_t bv3 = *(const bf16x8_t*)(bg + 3 * plane + o);
    acc[0][0] = mfma16(av0, bv0, acc[0][0]);
    acc[0][1] = mfma16(av0, bv1, acc[0][1]);
    acc[0][2] = mfma16(av0, bv2, acc[0][2]);
    acc[0][3] = mfma16(av0, bv3, acc[0][3]);
    acc[1][0] = mfma16(av1, bv0, acc[1][0]);
    acc[1][1] = mfma16(av1, bv1, acc[1][1]);
    acc[1][2] = mfma16(av1, bv2, acc[1][2]);
    acc[1][3] = mfma16(av1, bv3, acc[1][3]);
  }

  // C/D: col = lane&15, row = (lane>>4)*4 + reg
  const int lh = l >> 4, lr = l & 15;
  float* Pb = P + (size_t)(mw * 32 + lh * 4) * NCOL + nb4 * 64 + lr;
#pragma unroll
  for (int rb = 0; rb < 2; ++rb)
#pragma unroll
    for (int sub = 0; sub < 4; ++sub)
#pragma unroll
      for (int jj = 0; jj < 4; ++jj)
        Pb[(size_t)(rb * 16 + jj) * NCOL + sub * 16] = acc[rb][sub][jj];
}

// ---------- K4: sum split-K partials + bias -> d_out
__global__ __launch_bounds__(256) void combine_kernel(
    const float* __restrict__ bias, const float* __restrict__ p_imu,
    const float* __restrict__ p_emg, float* __restrict__ out, int B) {
  const int b = blockIdx.x, m = blockIdx.y, j = threadIdx.x;
  const size_t n = (size_t)B * NCOL;
  const size_t o = (size_t)b * NCOL + j;
  if (m == 0) {
    float v = bias[j];
#pragma unroll
    for (int c = 0; c < NCI; ++c) v += p_imu[c * n + o];
    out[o] = v;
  } else {
    float v = bias[NCOL + j];
#pragma unroll
    for (int c = 0; c < NCE; ++c) v += p_emg[c * n + o];
    out[n + o] = v;
  }
}

extern "C" void kernel_launch(void* const* d_in, const int* in_sizes, int n_in,
                              void* d_out, int out_size, void* d_ws, size_t ws_size,
                              hipStream_t stream) {
  const float* x_imu     = (const float*)d_in[0];
  const float* x_emg     = (const float*)d_in[1];
  const int*   lens      = (const int*)d_in[2];
  const float* w_emb_imu = (const float*)d_in[3];
  const float* b_emb_imu = (const float*)d_in[4];
  const float* w_emb_emg = (const float*)d_in[5];
  const float* b_emb_emg = (const float*)d_in[6];
  const float* w_proj    = (const float*)d_in[7];
  const float* b_proj    = (const float*)d_in[8];
  float* out = (float*)d_out;

  const int B = in_sizes[2];
  const int T = in_sizes[0] / (B * CIMU);

  char* ws = (char*)d_ws;
  __bf16* wpk_imu = (__bf16*)ws;  ws += (size_t)NCOL * KIMU * 2;
  __bf16* wpk_emg = (__bf16*)ws;  ws += (size_t)NCOL * KEMG * 2;
  float*  bias    = (float*)ws;   ws += 2 * NCOL * 4;
  float*  bpart   = (float*)ws;   ws += (size_t)2 * NEWL * NCOL * 4;
  __bf16* xa_imu  = (__bf16*)ws;  ws += (size_t)B * KIMU * 2;
  __bf16* xa_emg  = (__bf16*)ws;  ws += (size_t)B * KEMG * 2;
  float*  p_imu   = (float*)ws;   ws += (size_t)NCI * B * NCOL * 4;
  float*  p_emg   = (float*)ws;   ws += (size_t)NCE * B * NCOL * 4;

  wcomb_kernel<<<dim3(NEWL, 2), 256, 0, stream>>>(
      w_emb_imu, w_emb_emg, b_emb_imu, b_emb_emg, w_proj, wpk_imu, wpk_emg, bpart);
  bias_reduce_kernel<<<2, 256, 0, stream>>>(b_proj, bpart, bias);
  interp_kernel<<<B * NEWL / 8, 256, 0, stream>>>(x_imu, x_emg, lens,
                                                  xa_imu, xa_emg, B, T);
  const int units = (NCI + NCE) * (B / 32) * 4;  // 3072 waves
  mfma_gemm_kernel<<<units / 4, 256, 0, stream>>>(xa_imu, xa_emg, wpk_imu, wpk_emg,
                                                  p_imu, p_emg, B);
  combine_kernel<<<dim3(B, 2), 256, 0, stream>>>(bias, p_imu, p_emg, out, B);
}

// Round 5
// 101.763 us; speedup vs baseline: 1.2697x; 1.2697x over previous
//
#include <hip/hip_runtime.h>

#define NEWL 150
#define EMBD 64
#define NCOL 256
#define CIMU 48
#define CEMG 16

#define KIMU (NEWL * CIMU)  // 7200
#define KEMG (NEWL * CEMG)  // 2400
#define KSTI (KIMU / 32)    // 225 k-steps imu
#define KSTE (KEMG / 32)    // 75  k-steps emg
#define KSC 25              // k-steps per split-K chunk (K=800)
#define NCI (KSTI / KSC)    // 9 imu chunks
#define NCE (KSTE / KSC)    // 3 emg chunks

typedef __bf16 bf16x8_t __attribute__((ext_vector_type(8)));
typedef __bf16 bf16x4_t __attribute__((ext_vector_type(4)));
typedef float f32x4_t __attribute__((ext_vector_type(4)));

__device__ __forceinline__ f32x4_t mfma16(bf16x8_t a, bf16x8_t b, f32x4_t c) {
  return __builtin_amdgcn_mfma_f32_16x16x32_bf16(a, b, c, 0, 0, 0);
}

// ---------- K0: combined weights packed in MFMA B-fragment order + bias partials.
// W_pack[cb][ks][lane=h*16+(col&15)][u]  where k = ks*32 + h*8 + u
template <int C, int KST>
__device__ void wcomb_body(const float* __restrict__ wemb,
                           const float* __restrict__ wreg_src,
                           __bf16* __restrict__ wpk, int s, int j) {
  float wreg[EMBD];
#pragma unroll
  for (int e = 0; e < EMBD; ++e) wreg[e] = wreg_src[(size_t)e * NCOL];
  const int cb = j >> 4, lr = j & 15;
#pragma unroll
  for (int q = 0; q < C / 8; ++q) {
    const int kq = (s * C) / 8 + q;  // k/8
    const int ks = kq >> 2, h = kq & 3;
    bf16x8_t tv;
#pragma unroll
    for (int u = 0; u < 8; ++u) {
      const float* we = wemb + (q * 8 + u) * EMBD;
      float acc = 0.f;
#pragma unroll
      for (int e = 0; e < EMBD; ++e) acc = fmaf(we[e], wreg[e], acc);
      tv[u] = (__bf16)acc;
    }
    *(bf16x8_t*)(wpk + (((size_t)cb * KST + ks) * 64 + h * 16 + lr) * 8) = tv;
  }
}

__global__ __launch_bounds__(256) void wcomb_kernel(
    const float* __restrict__ w_emb_imu, const float* __restrict__ w_emb_emg,
    const float* __restrict__ b_emb_imu, const float* __restrict__ b_emb_emg,
    const float* __restrict__ w_proj,
    __bf16* __restrict__ wpk_imu, __bf16* __restrict__ wpk_emg,
    float* __restrict__ bpart) {
  const int s = blockIdx.x;   // 0..149
  const int m = blockIdx.y;   // 0 = imu, 1 = emg
  const int j = threadIdx.x;  // output column 0..255
  const float* wp_base = w_proj + (size_t)s * EMBD * NCOL + j;
  const float* be = (m == 0) ? b_emb_imu : b_emb_emg;
  float bacc = 0.f;
#pragma unroll
  for (int e = 0; e < EMBD; ++e) bacc = fmaf(be[e], wp_base[(size_t)e * NCOL], bacc);
  bpart[((size_t)m * NEWL + s) * NCOL + j] = bacc;
  if (m == 0)
    wcomb_body<CIMU, KSTI>(w_emb_imu, wp_base, wpk_imu, s, j);
  else
    wcomb_body<CEMG, KSTE>(w_emb_emg, wp_base, wpk_emg, s, j);
}

__global__ __launch_bounds__(256) void bias_reduce_kernel(
    const float* __restrict__ b_proj, const float* __restrict__ bpart,
    float* __restrict__ bias) {
  const int m = blockIdx.x, j = threadIdx.x;
  float acc = b_proj[j];
  for (int s = 0; s < NEWL; ++s) acc += bpart[((size_t)m * NEWL + s) * NCOL + j];
  bias[m * NCOL + j] = acc;
}

// ---------- K2: ragged interp, one wave per (16-b group, s).
// Gather raw rows, lerp (partner-lane shfl), transpose in wave-private LDS,
// store packed-A as coalesced 256B granules.
__global__ __launch_bounds__(256) void interp_kernel(
    const float* __restrict__ x_imu, const float* __restrict__ x_emg,
    const int* __restrict__ lens,
    __bf16* __restrict__ xa_imu, __bf16* __restrict__ xa_emg, int B, int T) {
  __shared__ __bf16 lds[4][16 * 56 + 16 * 24];  // per-wave imu [16][56] + emg [16][24]
  const int tid = threadIdx.x, w = tid >> 6, lane = tid & 63;
  const int gw = blockIdx.x * 4 + w;
  const int mb = gw / NEWL;           // 16-row plane index, 0..B/16-1
  const int s = gw - mb * NEWL;
  if (mb >= (B >> 4)) return;
  const int bl = lane >> 2, q = lane & 3;
  const int b = mb * 16 + bl;

  const int len = lens[b];
  const float scale = (float)len / 150.0f;
  float src = ((float)s + 0.5f) * scale - 0.5f;
  src = fmaxf(src, 0.0f);
  int i0 = (int)floorf(src);
  i0 = min(i0, len - 1);
  const int i1 = min(i0 + 1, len - 1);
  const float wgt = src - (float)i0;

  // gather: q<2 -> row i0, q>=2 -> row i1; (q&1) selects half of the row
  const int row = (q < 2) ? i0 : i1;
  const float* pim = x_imu + ((size_t)b * T + row) * CIMU + (q & 1) * 24;
  const float* pem = x_emg + ((size_t)b * T + row) * CEMG + (q & 1) * 8;
  float4 av[6], ev[2];
#pragma unroll
  for (int t = 0; t < 6; ++t) av[t] = *(const float4*)(pim + t * 4);
#pragma unroll
  for (int t = 0; t < 2; ++t) ev[t] = *(const float4*)(pem + t * 4);

  // partner: same (bl, half) but row i1  -> lane (bl*4) + 2 + (q&1)
  const int srcl = (lane & ~3) + 2 + (q & 1);
  float4 pv[6], pe[2];
#pragma unroll
  for (int t = 0; t < 6; ++t) {
    pv[t].x = __shfl(av[t].x, srcl); pv[t].y = __shfl(av[t].y, srcl);
    pv[t].z = __shfl(av[t].z, srcl); pv[t].w = __shfl(av[t].w, srcl);
  }
#pragma unroll
  for (int t = 0; t < 2; ++t) {
    pe[t].x = __shfl(ev[t].x, srcl); pe[t].y = __shfl(ev[t].y, srcl);
    pe[t].z = __shfl(ev[t].z, srcl); pe[t].w = __shfl(ev[t].w, srcl);
  }

  __bf16* li = &lds[w][0];
  __bf16* le = li + 16 * 56;
  if (q < 2) {
    const float om = 1.0f - wgt;
#pragma unroll
    for (int t = 0; t < 6; ++t) {
      bf16x4_t o;
      o[0] = (__bf16)(av[t].x * om + pv[t].x * wgt);
      o[1] = (__bf16)(av[t].y * om + pv[t].y * wgt);
      o[2] = (__bf16)(av[t].z * om + pv[t].z * wgt);
      o[3] = (__bf16)(av[t].w * om + pv[t].w * wgt);
      *(bf16x4_t*)(li + bl * 56 + q * 24 + t * 4) = o;
    }
#pragma unroll
    for (int t = 0; t < 2; ++t) {
      bf16x4_t o;
      o[0] = (__bf16)(ev[t].x * om + pe[t].x * wgt);
      o[1] = (__bf16)(ev[t].y * om + pe[t].y * wgt);
      o[2] = (__bf16)(ev[t].z * om + pe[t].z * wgt);
      o[3] = (__bf16)(ev[t].w * om + pe[t].w * wgt);
      *(bf16x4_t*)(le + bl * 24 + q * 8 + t * 4) = o;
    }
  }
  // wave-private LDS: compiler-inserted lgkmcnt ordering suffices, no barrier.

  // packed-A store. granule kq = k/8; addr(bf16) = mb*KST*512 + kq*128 + r*8
  {
    const int j0 = lane >> 4, r = lane & 15;  // round 0: imu granules j=0..3
    const bf16x8_t v = *(const bf16x8_t*)(li + r * 56 + j0 * 8);
    *(bf16x8_t*)(xa_imu + (size_t)mb * KSTI * 512 + (size_t)(6 * s + j0) * 128 + r * 8) = v;
  }
  if (lane < 32) {  // round 1a: imu granules j=4,5
    const int j1 = 4 + (lane >> 4), r = lane & 15;
    const bf16x8_t v = *(const bf16x8_t*)(li + r * 56 + j1 * 8);
    *(bf16x8_t*)(xa_imu + (size_t)mb * KSTI * 512 + (size_t)(6 * s + j1) * 128 + r * 8) = v;
  } else {          // round 1b: emg granules je=0,1
    const int idx = lane - 32;
    const int je = idx >> 4, r = idx & 15;
    const bf16x8_t v = *(const bf16x8_t*)(le + r * 24 + je * 8);
    *(bf16x8_t*)(xa_emg + (size_t)mb * KSTE * 512 + (size_t)(2 * s + je) * 128 + r * 8) = v;
  }
}

// ---------- K3: barrier-free register-streamed MFMA GEMM.
// One block = one (32-row m-tile, k-chunk); 4 waves = 4 column quarters
// sharing the same A-chunk via L1/L2. No LDS.
__global__ __launch_bounds__(256) void mfma_gemm_kernel(
    const __bf16* __restrict__ xa_imu, const __bf16* __restrict__ xa_emg,
    const __bf16* __restrict__ wpk_imu, const __bf16* __restrict__ wpk_emg,
    float* __restrict__ p_imu, float* __restrict__ p_emg, int B) {
  const int mtiles = B >> 5;             // 64 m-tiles of 32 rows
  const int c = blockIdx.x / mtiles;     // chunk 0..11
  const int mt = blockIdx.x - c * mtiles;
  const int nb4 = threadIdx.x >> 6;      // wave = column quarter
  const int l = threadIdx.x & 63;

  const __bf16* A;
  const __bf16* Wp;
  float* P;
  int KST, kc;
  if (c < NCI) {
    kc = c; A = xa_imu; Wp = wpk_imu; KST = KSTI;
    P = p_imu + (size_t)kc * B * NCOL;
  } else {
    kc = c - NCI; A = xa_emg; Wp = wpk_emg; KST = KSTE;
    P = p_emg + (size_t)kc * B * NCOL;
  }
  const int ks0 = kc * KSC;
  const size_t plane = (size_t)KST * 512;

  const __bf16* ap0 = A + (size_t)(mt * 2) * plane + ((size_t)ks0 * 64 + l) * 8;
  const __bf16* ap1 = ap0 + plane;
  const __bf16* bg = Wp + (size_t)(nb4 * 4) * plane + ((size_t)ks0 * 64 + l) * 8;

  f32x4_t z = {0.f, 0.f, 0.f, 0.f};
  f32x4_t acc[2][4];
#pragma unroll
  for (int i = 0; i < 2; ++i)
#pragma unroll
    for (int jj = 0; jj < 4; ++jj) acc[i][jj] = z;

#pragma unroll 5
  for (int ks = 0; ks < KSC; ++ks) {
    const size_t o = (size_t)ks * 512;
    const bf16x8_t av0 = *(const bf16x8_t*)(ap0 + o);
    const bf16x8_t av1 = *(const bf16x8_t*)(ap1 + o);
    const bf16x8_t bv0 = *(const bf16x8_t*)(bg + o);
    const bf16x8_t bv1 = *(const bf16x8_t*)(bg + plane + o);
    const bf16x8_t bv2 = *(const bf16x8_t*)(bg + 2 * plane + o);
    const bf16x8_t bv3 = *(const bf16x8_t*)(bg + 3 * plane + o);
    acc[0][0] = mfma16(av0, bv0, acc[0][0]);
    acc[0][1] = mfma16(av0, bv1, acc[0][1]);
    acc[0][2] = mfma16(av0, bv2, acc[0][2]);
    acc[0][3] = mfma16(av0, bv3, acc[0][3]);
    acc[1][0] = mfma16(av1, bv0, acc[1][0]);
    acc[1][1] = mfma16(av1, bv1, acc[1][1]);
    acc[1][2] = mfma16(av1, bv2, acc[1][2]);
    acc[1][3] = mfma16(av1, bv3, acc[1][3]);
  }

  // C/D: col = lane&15, row = (lane>>4)*4 + reg
  const int lh = l >> 4, lr = l & 15;
  float* Pb = P + (size_t)(mt * 32 + lh * 4) * NCOL + nb4 * 64 + lr;
#pragma unroll
  for (int rb = 0; rb < 2; ++rb)
#pragma unroll
    for (int sub = 0; sub < 4; ++sub)
#pragma unroll
      for (int jj = 0; jj < 4; ++jj)
        Pb[(size_t)(rb * 16 + jj) * NCOL + sub * 16] = acc[rb][sub][jj];
}

// ---------- K4: sum split-K partials + bias -> d_out
__global__ __launch_bounds__(256) void combine_kernel(
    const float* __restrict__ bias, const float* __restrict__ p_imu,
    const float* __restrict__ p_emg, float* __restrict__ out, int B) {
  const int b = blockIdx.x, m = blockIdx.y, j = threadIdx.x;
  const size_t n = (size_t)B * NCOL;
  const size_t o = (size_t)b * NCOL + j;
  if (m == 0) {
    float v = bias[j];
#pragma unroll
    for (int c = 0; c < NCI; ++c) v += p_imu[c * n + o];
    out[o] = v;
  } else {
    float v = bias[NCOL + j];
#pragma unroll
    for (int c = 0; c < NCE; ++c) v += p_emg[c * n + o];
    out[n + o] = v;
  }
}

extern "C" void kernel_launch(void* const* d_in, const int* in_sizes, int n_in,
                              void* d_out, int out_size, void* d_ws, size_t ws_size,
                              hipStream_t stream) {
  const float* x_imu     = (const float*)d_in[0];
  const float* x_emg     = (const float*)d_in[1];
  const int*   lens      = (const int*)d_in[2];
  const float* w_emb_imu = (const float*)d_in[3];
  const float* b_emb_imu = (const float*)d_in[4];
  const float* w_emb_emg = (const float*)d_in[5];
  const float* b_emb_emg = (const float*)d_in[6];
  const float* w_proj    = (const float*)d_in[7];
  const float* b_proj    = (const float*)d_in[8];
  float* out = (float*)d_out;

  const int B = in_sizes[2];
  const int T = in_sizes[0] / (B * CIMU);

  char* ws = (char*)d_ws;
  __bf16* wpk_imu = (__bf16*)ws;  ws += (size_t)NCOL * KIMU * 2;
  __bf16* wpk_emg = (__bf16*)ws;  ws += (size_t)NCOL * KEMG * 2;
  float*  bias    = (float*)ws;   ws += 2 * NCOL * 4;
  float*  bpart   = (float*)ws;   ws += (size_t)2 * NEWL * NCOL * 4;
  __bf16* xa_imu  = (__bf16*)ws;  ws += (size_t)B * KIMU * 2;
  __bf16* xa_emg  = (__bf16*)ws;  ws += (size_t)B * KEMG * 2;
  float*  p_imu   = (float*)ws;   ws += (size_t)NCI * B * NCOL * 4;
  float*  p_emg   = (float*)ws;   ws += (size_t)NCE * B * NCOL * 4;

  wcomb_kernel<<<dim3(NEWL, 2), 256, 0, stream>>>(
      w_emb_imu, w_emb_emg, b_emb_imu, b_emb_emg, w_proj, wpk_imu, wpk_emg, bpart);
  bias_reduce_kernel<<<2, 256, 0, stream>>>(b_proj, bpart, bias);
  interp_kernel<<<(B / 16) * NEWL / 4, 256, 0, stream>>>(x_imu, x_emg, lens,
                                                         xa_imu, xa_emg, B, T);
  const int blocks = (NCI + NCE) * (B / 32);  // 768
  mfma_gemm_kernel<<<blocks, 256, 0, stream>>>(xa_imu, xa_emg, wpk_imu, wpk_emg,
                                               p_imu, p_emg, B);
  combine_kernel<<<dim3(B, 2), 256, 0, stream>>>(bias, p_imu, p_emg, out, B);
}

// Round 6
// 95.089 us; speedup vs baseline: 1.3588x; 1.0702x over previous
//
#include <hip/hip_runtime.h>

#define NEWL 150
#define EMBD 64
#define NCOL 256
#define CIMU 48
#define CEMG 16

#define KIMU (NEWL * CIMU)  // 7200
#define KEMG (NEWL * CEMG)  // 2400
#define KSTI 225            // total k-steps (32-wide) imu
#define KSTE 75             // total k-steps emg
#define NCI 5               // imu s-chunks (30 s each -> 45 ksteps)
#define SCH_I 30
#define NG_I 15             // groups per imu chunk (2 s -> 3 ksteps each)
#define NG_E 25             // groups per emg chunk (6 s -> 3 ksteps each)

typedef __bf16 bf16x8_t __attribute__((ext_vector_type(8)));
typedef __bf16 bf16x4_t __attribute__((ext_vector_type(4)));
typedef float f32x4_t __attribute__((ext_vector_type(4)));

__device__ __forceinline__ f32x4_t mfma16(bf16x8_t a, bf16x8_t b, f32x4_t c) {
  return __builtin_amdgcn_mfma_f32_16x16x32_bf16(a, b, c, 0, 0, 0);
}

// ---------- K0: combined weights packed in MFMA B-fragment order + bias partials
// (unchanged from R5 — verified). W_pack[cb][ks][lane=h*16+(col&15)][u], k=ks*32+h*8+u
template <int C, int KST>
__device__ void wcomb_body(const float* __restrict__ wemb,
                           const float* __restrict__ wreg_src,
                           __bf16* __restrict__ wpk, int s, int j) {
  float wreg[EMBD];
#pragma unroll
  for (int e = 0; e < EMBD; ++e) wreg[e] = wreg_src[(size_t)e * NCOL];
  const int cb = j >> 4, lr = j & 15;
#pragma unroll
  for (int q = 0; q < C / 8; ++q) {
    const int kq = (s * C) / 8 + q;
    const int ks = kq >> 2, h = kq & 3;
    bf16x8_t tv;
#pragma unroll
    for (int u = 0; u < 8; ++u) {
      const float* we = wemb + (q * 8 + u) * EMBD;
      float acc = 0.f;
#pragma unroll
      for (int e = 0; e < EMBD; ++e) acc = fmaf(we[e], wreg[e], acc);
      tv[u] = (__bf16)acc;
    }
    *(bf16x8_t*)(wpk + (((size_t)cb * KST + ks) * 64 + h * 16 + lr) * 8) = tv;
  }
}

__global__ __launch_bounds__(256) void wcomb_kernel(
    const float* __restrict__ w_emb_imu, const float* __restrict__ w_emb_emg,
    const float* __restrict__ b_emb_imu, const float* __restrict__ b_emb_emg,
    const float* __restrict__ w_proj,
    __bf16* __restrict__ wpk_imu, __bf16* __restrict__ wpk_emg,
    float* __restrict__ bpart) {
  const int s = blockIdx.x, m = blockIdx.y, j = threadIdx.x;
  const float* wp_base = w_proj + (size_t)s * EMBD * NCOL + j;
  const float* be = (m == 0) ? b_emb_imu : b_emb_emg;
  float bacc = 0.f;
#pragma unroll
  for (int e = 0; e < EMBD; ++e) bacc = fmaf(be[e], wp_base[(size_t)e * NCOL], bacc);
  bpart[((size_t)m * NEWL + s) * NCOL + j] = bacc;
  if (m == 0)
    wcomb_body<CIMU, KSTI>(w_emb_imu, wp_base, wpk_imu, s, j);
  else
    wcomb_body<CEMG, KSTE>(w_emb_emg, wp_base, wpk_emg, s, j);
}

// ---------- K1: fused ragged-interp + MFMA GEMM (+ bias-reduce tail block)
__global__ __launch_bounds__(256) void fused_kernel(
    const float* __restrict__ x_imu, const float* __restrict__ x_emg,
    const int* __restrict__ lens,
    const __bf16* __restrict__ wpk_imu, const __bf16* __restrict__ wpk_emg,
    const float* __restrict__ b_proj, const float* __restrict__ bpart,
    float* __restrict__ p_imu, float* __restrict__ p_emg,
    float* __restrict__ bias, int B, int T) {
  const int bid = blockIdx.x;
  const int span = B >> 4;  // blocks per chunk (mtiles*2)
  const int mts = B >> 5;   // 32-row m-tiles
  if (bid == (NCI + 1) * span) {  // bias tail block
    const int j = threadIdx.x;
#pragma unroll
    for (int m = 0; m < 2; ++m) {
      float acc = b_proj[j];
      for (int s = 0; s < NEWL; ++s) acc += bpart[((size_t)m * NEWL + s) * NCOL + j];
      bias[m * NCOL + j] = acc;
    }
    return;
  }

  __shared__ __bf16 lds[2][2][3][512];  // [buf][row-plane][ks][lane*8]

  const int tid = threadIdx.x;
  const int wv = tid >> 6, l = tid & 63;

  bool is_imu;
  int c, r;
  if (bid < NCI * span) { is_imu = true; c = bid / span; r = bid - c * span; }
  else { is_imu = false; c = 0; r = bid - NCI * span; }
  const int nh = r / mts, mt = r - nh * mts;

  const __bf16* Wp = is_imu ? wpk_imu : wpk_emg;
  const int KST = is_imu ? KSTI : KSTE;
  const int ks0 = is_imu ? c * 45 : 0;
  const int NG = is_imu ? NG_I : NG_E;
  float* P = is_imu ? (p_imu + (size_t)c * B * NCOL) : p_emg;

  const size_t PS = (size_t)KST * 512;  // B fragment-plane stride (bf16)
  const __bf16* bg = Wp + ((size_t)(nh * 8 + wv * 2) * KST + ks0) * 512 + l * 8;

  // gather thread mappings
  const int q = tid & 3, sl = (tid >> 2) & 1, bli = tid >> 3;  // imu: 4 thr/(b,s)
  const int ble = tid / 6, se = tid - ble * 6;                 // emg: 1 thr/(b,s), tid<192
  const bool act = is_imu || (tid < 192);
  const int b_g = mt * 32 + (is_imu ? bli : ble);
  int lenv = 1;
  float scale = 0.f;
  if (act) { lenv = lens[b_g]; scale = (float)lenv / 150.0f; }
  const int prt_i = (l & ~3) | 2 | (q & 1);  // imu lerp partner lane

  float gr[2][32];   // gather reg slots (imu uses 24, emg 32)
  float wS[2];       // lerp weights per slot
  bf16x8_t bB[2][6]; // B fragment slots (2 planes x 3 ksteps)
  f32x4_t acc00 = {0.f, 0.f, 0.f, 0.f}, acc01 = acc00, acc10 = acc00, acc11 = acc00;

#define ISSUE_GI(g2, Pp) do {                                                   \
    const int s_ = c * SCH_I + (g2) * 2 + sl;                                   \
    float src_ = fmaxf(((float)s_ + 0.5f) * scale - 0.5f, 0.0f);                \
    int i0_ = min((int)floorf(src_), lenv - 1);                                 \
    int i1_ = min(i0_ + 1, lenv - 1);                                           \
    wS[Pp] = src_ - (float)i0_;                                                 \
    const float* p_ =                                                           \
        x_imu + ((size_t)b_g * T + ((q < 2) ? i0_ : i1_)) * CIMU + (q & 1) * 24;\
    _Pragma("unroll")                                                           \
    for (int t = 0; t < 6; ++t) {                                               \
      float4 v_ = *(const float4*)(p_ + t * 4);                                 \
      gr[Pp][t * 4 + 0] = v_.x; gr[Pp][t * 4 + 1] = v_.y;                       \
      gr[Pp][t * 4 + 2] = v_.z; gr[Pp][t * 4 + 3] = v_.w;                       \
    }                                                                           \
  } while (0)

#define LERP_WI(Pp, BUF) do {                                                   \
    const float wg_ = wS[Pp], om_ = 1.0f - wg_;                                 \
    _Pragma("unroll")                                                           \
    for (int t = 0; t < 6; ++t) {                                               \
      float a0_ = gr[Pp][t * 4 + 0], a1_ = gr[Pp][t * 4 + 1];                   \
      float a2_ = gr[Pp][t * 4 + 2], a3_ = gr[Pp][t * 4 + 3];                   \
      float p0_ = __shfl(a0_, prt_i), p1_ = __shfl(a1_, prt_i);                 \
      float p2_ = __shfl(a2_, prt_i), p3_ = __shfl(a3_, prt_i);                 \
      if (q < 2) {                                                              \
        bf16x4_t o_;                                                            \
        o_[0] = (__bf16)(a0_ * om_ + p0_ * wg_);                                \
        o_[1] = (__bf16)(a1_ * om_ + p1_ * wg_);                                \
        o_[2] = (__bf16)(a2_ * om_ + p2_ * wg_);                                \
        o_[3] = (__bf16)(a3_ * om_ + p3_ * wg_);                                \
        const int kq_ = sl * 6 + q * 3 + (t >> 1);                              \
        *(bf16x4_t*)(&lds[BUF][bli >> 4][kq_ >> 2]                              \
                         [((kq_ & 3) * 16 + (bli & 15)) * 8 + (t & 1) * 4]) = o_;\
      }                                                                         \
    }                                                                           \
  } while (0)

#define ISSUE_GE(g2, Pp) do { if (tid < 192) {                                  \
    const int s_ = (g2) * 6 + se;                                               \
    float src_ = fmaxf(((float)s_ + 0.5f) * scale - 0.5f, 0.0f);                \
    int i0_ = min((int)floorf(src_), lenv - 1);                                 \
    int i1_ = min(i0_ + 1, lenv - 1);                                           \
    wS[Pp] = src_ - (float)i0_;                                                 \
    const float* p0_ = x_emg + ((size_t)b_g * T + i0_) * CEMG;                  \
    const float* p1_ = x_emg + ((size_t)b_g * T + i1_) * CEMG;                  \
    _Pragma("unroll")                                                           \
    for (int t = 0; t < 4; ++t) {                                               \
      float4 v_ = *(const float4*)(p0_ + t * 4);                                \
      gr[Pp][t * 4 + 0] = v_.x; gr[Pp][t * 4 + 1] = v_.y;                       \
      gr[Pp][t * 4 + 2] = v_.z; gr[Pp][t * 4 + 3] = v_.w;                       \
      float4 u_ = *(const float4*)(p1_ + t * 4);                                \
      gr[Pp][16 + t * 4 + 0] = u_.x; gr[Pp][16 + t * 4 + 1] = u_.y;             \
      gr[Pp][16 + t * 4 + 2] = u_.z; gr[Pp][16 + t * 4 + 3] = u_.w;             \
    }                                                                           \
  } } while (0)

#define LERP_WE(Pp, BUF) do { if (tid < 192) {                                  \
    const float wg_ = wS[Pp], om_ = 1.0f - wg_;                                 \
    _Pragma("unroll")                                                           \
    for (int t2 = 0; t2 < 2; ++t2) {                                            \
      bf16x8_t o_;                                                              \
      _Pragma("unroll")                                                         \
      for (int u = 0; u < 8; ++u)                                               \
        o_[u] = (__bf16)(gr[Pp][t2 * 8 + u] * om_ +                             \
                         gr[Pp][16 + t2 * 8 + u] * wg_);                        \
      const int kq_ = se * 2 + t2;                                              \
      *(bf16x8_t*)(&lds[BUF][ble >> 4][kq_ >> 2]                                \
                       [((kq_ & 3) * 16 + (ble & 15)) * 8]) = o_;               \
    }                                                                           \
  } } while (0)

#define ISSUE_B(g1, Ss) do {                                                    \
    const __bf16* pb_ = bg + (size_t)((g1) * 3) * 512;                          \
    _Pragma("unroll")                                                           \
    for (int ks = 0; ks < 3; ++ks) {                                            \
      bB[Ss][ks * 2 + 0] = *(const bf16x8_t*)(pb_ + (size_t)ks * 512);          \
      bB[Ss][ks * 2 + 1] = *(const bf16x8_t*)(pb_ + PS + (size_t)ks * 512);     \
    }                                                                           \
  } while (0)

#define COMPUTE(Pp) do {                                                        \
    _Pragma("unroll")                                                           \
    for (int ks = 0; ks < 3; ++ks) {                                            \
      bf16x8_t a0_ = *(const bf16x8_t*)(&lds[Pp][0][ks][l * 8]);                \
      bf16x8_t a1_ = *(const bf16x8_t*)(&lds[Pp][1][ks][l * 8]);                \
      acc00 = mfma16(a0_, bB[Pp][ks * 2 + 0], acc00);                           \
      acc01 = mfma16(a0_, bB[Pp][ks * 2 + 1], acc01);                           \
      acc10 = mfma16(a1_, bB[Pp][ks * 2 + 0], acc10);                           \
      acc11 = mfma16(a1_, bB[Pp][ks * 2 + 1], acc11);                           \
    }                                                                           \
  } while (0)

  // prologue: 2 gather sets + 1 B set in flight, group 0 staged
  if (is_imu) { ISSUE_GI(0, 0); ISSUE_GI(1, 1); }
  else        { ISSUE_GE(0, 0); ISSUE_GE(1, 1); }
  ISSUE_B(0, 0);
  if (is_imu) LERP_WI(0, 0); else LERP_WE(0, 0);
  __syncthreads();

  for (int g = 0; g < NG; g += 2) {
    if (g + 2 < NG) { if (is_imu) ISSUE_GI(g + 2, 0); else ISSUE_GE(g + 2, 0); }
    if (g + 1 < NG) ISSUE_B(g + 1, 1);
    COMPUTE(0);
    if (g + 1 < NG) { if (is_imu) LERP_WI(1, 1); else LERP_WE(1, 1); }
    __syncthreads();
    if (g + 1 < NG) {
      if (g + 3 < NG) { if (is_imu) ISSUE_GI(g + 3, 1); else ISSUE_GE(g + 3, 1); }
      if (g + 2 < NG) ISSUE_B(g + 2, 0);
      COMPUTE(1);
      if (g + 2 < NG) { if (is_imu) LERP_WI(0, 0); else LERP_WE(0, 0); }
      __syncthreads();
    }
  }

  // C/D: col = lane&15, row = (lane>>4)*4 + reg
  const int lh = l >> 4, lr = l & 15;
  float* Pb = P + (size_t)(mt * 32 + lh * 4) * NCOL + nh * 128 + wv * 32 + lr;
#pragma unroll
  for (int jj = 0; jj < 4; ++jj) {
    Pb[(size_t)jj * NCOL] = acc00[jj];
    Pb[(size_t)jj * NCOL + 16] = acc01[jj];
    Pb[(size_t)(16 + jj) * NCOL] = acc10[jj];
    Pb[(size_t)(16 + jj) * NCOL + 16] = acc11[jj];
  }
#undef ISSUE_GI
#undef LERP_WI
#undef ISSUE_GE
#undef LERP_WE
#undef ISSUE_B
#undef COMPUTE
}

// ---------- K2: sum split-K partials + bias -> d_out
__global__ __launch_bounds__(256) void combine_kernel(
    const float* __restrict__ bias, const float* __restrict__ p_imu,
    const float* __restrict__ p_emg, float* __restrict__ out, int B) {
  const int b = blockIdx.x, m = blockIdx.y, j = threadIdx.x;
  const size_t n = (size_t)B * NCOL;
  const size_t o = (size_t)b * NCOL + j;
  if (m == 0) {
    float v = bias[j];
#pragma unroll
    for (int c = 0; c < NCI; ++c) v += p_imu[c * n + o];
    out[o] = v;
  } else {
    out[n + o] = bias[NCOL + j] + p_emg[o];
  }
}

extern "C" void kernel_launch(void* const* d_in, const int* in_sizes, int n_in,
                              void* d_out, int out_size, void* d_ws, size_t ws_size,
                              hipStream_t stream) {
  const float* x_imu     = (const float*)d_in[0];
  const float* x_emg     = (const float*)d_in[1];
  const int*   lens      = (const int*)d_in[2];
  const float* w_emb_imu = (const float*)d_in[3];
  const float* b_emb_imu = (const float*)d_in[4];
  const float* w_emb_emg = (const float*)d_in[5];
  const float* b_emb_emg = (const float*)d_in[6];
  const float* w_proj    = (const float*)d_in[7];
  const float* b_proj    = (const float*)d_in[8];
  float* out = (float*)d_out;

  const int B = in_sizes[2];
  const int T = in_sizes[0] / (B * CIMU);

  char* ws = (char*)d_ws;
  __bf16* wpk_imu = (__bf16*)ws;  ws += (size_t)NCOL * KIMU * 2;
  __bf16* wpk_emg = (__bf16*)ws;  ws += (size_t)NCOL * KEMG * 2;
  float*  bias    = (float*)ws;   ws += 2 * NCOL * 4;
  float*  bpart   = (float*)ws;   ws += (size_t)2 * NEWL * NCOL * 4;
  float*  p_imu   = (float*)ws;   ws += (size_t)NCI * B * NCOL * 4;
  float*  p_emg   = (float*)ws;   ws += (size_t)B * NCOL * 4;

  wcomb_kernel<<<dim3(NEWL, 2), 256, 0, stream>>>(
      w_emb_imu, w_emb_emg, b_emb_imu, b_emb_emg, w_proj, wpk_imu, wpk_emg, bpart);
  const int span = B >> 4;                    // 128
  const int nblk = (NCI + 1) * span + 1;      // 769
  fused_kernel<<<nblk, 256, 0, stream>>>(x_imu, x_emg, lens, wpk_imu, wpk_emg,
                                         b_proj, bpart, p_imu, p_emg, bias, B, T);
  combine_kernel<<<dim3(B, 2), 256, 0, stream>>>(bias, p_imu, p_emg, out, B);
}